// Round 1
// baseline (515.910 us; speedup 1.0000x reference)
//
#include <hip/hip_runtime.h>
#include <hip/hip_bf16.h>
#include <stdint.h>

typedef __bf16 bf16;
typedef __bf16 bf16x4 __attribute__((ext_vector_type(4)));
typedef __bf16 bf16x8 __attribute__((ext_vector_type(8)));
typedef float  f32x4  __attribute__((ext_vector_type(4)));
typedef float  f32x2  __attribute__((ext_vector_type(2)));

#define NROWS 262144
#define GSEG  65536
#define DIN   512
#define DMID  256
#define DGAT  128
#define DOUT  256

// ---- workspace layout (bytes). Total needed ~438 MB. ----
#define OFF_W2T   0u           // [256][512] bf16 = 262144
#define OFF_W3T   262144u      // [128][256] bf16 = 65536
#define OFF_GWT   327680u      // [128][128] bf16 = 32768
#define OFF_BNS   360448u      // [256] f32
#define OFF_BNB   361472u      // [256] f32
#define OFF_RS    362496u      // [65537] int
#define OFF_H1    1048576u     // [NROWS][256] bf16 = 134217728
#define OFF_H2    135266304u   // [NROWS][128] f32  = 134217728
#define OFF_G     269484032u   // [NROWS][128] f32  = 134217728
#define OFF_E     403701760u   // [NROWS] f32       = 1048576
#define OFF_OBJ   404750336u   // [GSEG][128] f32   = 33554432  (end 438304768)

// XOR-swizzle element index within a row: flip bits 3..5 by row&7.
// Preserves contiguity of any aligned 8-element (16B) or 4-element (8B) block.
__device__ __forceinline__ int swz(int r, int k) { return k ^ ((r & 7) << 3); }

// ---------------- prep: fold BN, transpose+convert weights to bf16 [col][k] ----------------
__global__ __launch_bounds__(256) void k_prep(
    const float* __restrict__ w2, const float* __restrict__ w3, const float* __restrict__ gw,
    const float* __restrict__ b2, const float* __restrict__ bn_g, const float* __restrict__ bn_b,
    const float* __restrict__ bn_m, const float* __restrict__ bn_v,
    bf16* __restrict__ w2t, bf16* __restrict__ w3t, bf16* __restrict__ gwt,
    float* __restrict__ bnS, float* __restrict__ bnB) {
  int idx = blockIdx.x * 256 + threadIdx.x;
  if (idx < DIN * DMID) { int k = idx / DMID, n = idx % DMID; w2t[n * DIN + k] = (bf16)w2[idx]; }
  if (idx < DMID * DGAT) { int k = idx / DGAT, n = idx % DGAT; w3t[n * DMID + k] = (bf16)w3[idx]; }
  if (idx < DGAT * DGAT) { int k = idx / DGAT, n = idx % DGAT; gwt[n * DGAT + k] = (bf16)gw[idx]; }
  if (idx < DMID) {
    float s = bn_g[idx] * rsqrtf(bn_v[idx] + 1e-5f);
    bnS[idx] = s;
    bnB[idx] = s * (b2[idx] - bn_m[idx]) + bn_b[idx];
  }
}

// ---------------- segment boundaries from sorted seg_ids ----------------
__global__ __launch_bounds__(256) void k_rowstart(const int* __restrict__ seg, int* __restrict__ rs) {
  int i = blockIdx.x * 256 + threadIdx.x;
  if (i >= NROWS) return;
  int s = seg[i];
  if (i == 0) rs[s] = 0;
  else if (seg[i - 1] != s) rs[s] = i;
  if (i == NROWS - 1) rs[GSEG] = NROWS;
}

// ---------------- GEMM1: h1 = relu(bnS * (x@w2) + bnB), bf16 out ----------------
// tile 128x256 (full width), BK=64, 4 waves (2x2), wave tile 64x128
__global__ __launch_bounds__(256) void k_gemm1(
    const float* __restrict__ x, const bf16* __restrict__ w2t,
    const float* __restrict__ bnS, const float* __restrict__ bnB,
    bf16* __restrict__ h1) {
  __shared__ bf16 As[128 * 64];   // [row][k] swizzled
  __shared__ bf16 Bs[256 * 64];   // [col][k] swizzled
  const int t = threadIdx.x;
  const int mBase = blockIdx.x * 128;
  const int w = t >> 6, l = t & 63;
  const int wm = w >> 1, wn = w & 1;

  f32x4 acc[4][8];
  const f32x4 zero = {0.f, 0.f, 0.f, 0.f};
#pragma unroll
  for (int m = 0; m < 4; m++)
#pragma unroll
    for (int n = 0; n < 8; n++) acc[m][n] = zero;

  for (int kt = 0; kt < 8; ++kt) {
    __syncthreads();
    // stage A: 128x64 fp32 -> bf16 (convert in regs)
#pragma unroll
    for (int i = 0; i < 8; i++) {
      int flat = (i * 256 + t) * 4;
      int r = flat >> 6, k = flat & 63;
      float4 v = *(const float4*)(x + (size_t)(mBase + r) * DIN + kt * 64 + k);
      bf16x4 bv;
      bv[0] = (bf16)v.x; bv[1] = (bf16)v.y; bv[2] = (bf16)v.z; bv[3] = (bf16)v.w;
      *(bf16x4*)(As + r * 64 + swz(r, k)) = bv;
    }
    // stage B: 256 cols x 64 k of w2t (already bf16)
#pragma unroll
    for (int i = 0; i < 16; i++) {
      int flat = (i * 256 + t) * 4;
      int c = flat >> 6, k = flat & 63;
      bf16x4 bv = *(const bf16x4*)(w2t + (size_t)c * DIN + kt * 64 + k);
      *(bf16x4*)(Bs + c * 64 + swz(c, k)) = bv;
    }
    __syncthreads();
#pragma unroll
    for (int ks = 0; ks < 2; ++ks) {
      const int kofs = ks * 32 + (l >> 4) * 8;
      bf16x8 a[4], b[8];
#pragma unroll
      for (int m = 0; m < 4; m++) {
        int r = wm * 64 + m * 16 + (l & 15);
        a[m] = *(const bf16x8*)(As + r * 64 + swz(r, kofs));
      }
#pragma unroll
      for (int n = 0; n < 8; n++) {
        int c = wn * 128 + n * 16 + (l & 15);
        b[n] = *(const bf16x8*)(Bs + c * 64 + swz(c, kofs));
      }
#pragma unroll
      for (int m = 0; m < 4; m++)
#pragma unroll
        for (int n = 0; n < 8; n++)
          acc[m][n] = __builtin_amdgcn_mfma_f32_16x16x32_bf16(a[m], b[n], acc[m][n], 0, 0, 0);
    }
  }
  // epilogue: BN + ReLU -> bf16
#pragma unroll
  for (int n = 0; n < 8; n++) {
    int c = wn * 128 + n * 16 + (l & 15);
    float s = bnS[c], bb = bnB[c];
#pragma unroll
    for (int m = 0; m < 4; m++) {
      int rbase = mBase + wm * 64 + m * 16 + ((l >> 4) << 2);
#pragma unroll
      for (int q = 0; q < 4; q++) {
        float v = acc[m][n][q] * s + bb;
        v = v > 0.f ? v : 0.f;
        h1[(size_t)(rbase + q) * DMID + c] = (bf16)v;
      }
    }
  }
}

// ---------------- GEMM2+3 fused: h2 = relu(h1@w3+b3); g = h2@gw+gb; e = g@ga ----------------
// tile 128x128 (full width), 4 waves (2x2), wave tile 64x64
__global__ __launch_bounds__(256) void k_gemm23(
    const bf16* __restrict__ h1, const bf16* __restrict__ w3t, const bf16* __restrict__ gwt,
    const float* __restrict__ b3, const float* __restrict__ gb, const float* __restrict__ ga,
    float* __restrict__ h2, float* __restrict__ g, float* __restrict__ e) {
  __shared__ bf16 u[16384];        // 32KB union: phase1 As(8192)+Bs(8192); phase2 Hs(16384)
  __shared__ float eP[256];        // [row][wn] partial e
  bf16* As = u;
  bf16* Bs = u + 8192;
  bf16* Hs = u;
  const int t = threadIdx.x;
  const int mBase = blockIdx.x * 128;
  const int w = t >> 6, l = t & 63;
  const int wm = w >> 1, wn = w & 1;
  const f32x4 zero = {0.f, 0.f, 0.f, 0.f};

  f32x4 acc[4][4];
#pragma unroll
  for (int m = 0; m < 4; m++)
#pragma unroll
    for (int n = 0; n < 4; n++) acc[m][n] = zero;

  // phase 1: h2 = relu(h1 @ w3 + b3), K=256
  for (int kt = 0; kt < 4; ++kt) {
    __syncthreads();
#pragma unroll
    for (int i = 0; i < 8; i++) {
      int flat = (i * 256 + t) * 4;
      int r = flat >> 6, k = flat & 63;
      *(bf16x4*)(As + r * 64 + swz(r, k)) =
          *(const bf16x4*)(h1 + (size_t)(mBase + r) * DMID + kt * 64 + k);
    }
#pragma unroll
    for (int i = 0; i < 8; i++) {
      int flat = (i * 256 + t) * 4;
      int c = flat >> 6, k = flat & 63;
      *(bf16x4*)(Bs + c * 64 + swz(c, k)) =
          *(const bf16x4*)(w3t + (size_t)c * DMID + kt * 64 + k);
    }
    __syncthreads();
#pragma unroll
    for (int ks = 0; ks < 2; ++ks) {
      const int kofs = ks * 32 + (l >> 4) * 8;
      bf16x8 a[4], b[4];
#pragma unroll
      for (int m = 0; m < 4; m++) {
        int r = wm * 64 + m * 16 + (l & 15);
        a[m] = *(const bf16x8*)(As + r * 64 + swz(r, kofs));
      }
#pragma unroll
      for (int n = 0; n < 4; n++) {
        int c = wn * 64 + n * 16 + (l & 15);
        b[n] = *(const bf16x8*)(Bs + c * 64 + swz(c, kofs));
      }
#pragma unroll
      for (int m = 0; m < 4; m++)
#pragma unroll
        for (int n = 0; n < 4; n++)
          acc[m][n] = __builtin_amdgcn_mfma_f32_16x16x32_bf16(a[m], b[n], acc[m][n], 0, 0, 0);
    }
  }
  __syncthreads();  // all waves done reading As/Bs (Hs aliases them)
  // epilogue 1: relu+bias, write h2 fp32 global + bf16 into Hs (swizzled)
#pragma unroll
  for (int n = 0; n < 4; n++) {
    int c = wn * 64 + n * 16 + (l & 15);
    float bias = b3[c];
#pragma unroll
    for (int m = 0; m < 4; m++) {
      int rloc = wm * 64 + m * 16 + ((l >> 4) << 2);
#pragma unroll
      for (int q = 0; q < 4; q++) {
        float v = acc[m][n][q] + bias;
        v = v > 0.f ? v : 0.f;
        h2[(size_t)(mBase + rloc + q) * DGAT + c] = v;
        Hs[(rloc + q) * 128 + swz(rloc + q, c)] = (bf16)v;
      }
    }
  }
  __syncthreads();

  // phase 2: g = h2 @ gw + gb (K=128); gw B-frags streamed from L1/L2
  f32x4 gacc[4][4];
#pragma unroll
  for (int m = 0; m < 4; m++)
#pragma unroll
    for (int n = 0; n < 4; n++) gacc[m][n] = zero;
#pragma unroll
  for (int ks = 0; ks < 4; ++ks) {
    const int kofs = ks * 32 + (l >> 4) * 8;
    bf16x8 a[4], b[4];
#pragma unroll
    for (int m = 0; m < 4; m++) {
      int r = wm * 64 + m * 16 + (l & 15);
      a[m] = *(const bf16x8*)(Hs + r * 128 + swz(r, kofs));
    }
#pragma unroll
    for (int n = 0; n < 4; n++) {
      int c = wn * 64 + n * 16 + (l & 15);
      b[n] = *(const bf16x8*)(gwt + (size_t)c * DGAT + kofs);
    }
#pragma unroll
    for (int m = 0; m < 4; m++)
#pragma unroll
      for (int n = 0; n < 4; n++)
        gacc[m][n] = __builtin_amdgcn_mfma_f32_16x16x32_bf16(a[m], b[n], gacc[m][n], 0, 0, 0);
  }
  // epilogue 2: g write + e = g . ga (partial per wave, reduce)
  float ep[4][4];
#pragma unroll
  for (int m = 0; m < 4; m++)
#pragma unroll
    for (int q = 0; q < 4; q++) ep[m][q] = 0.f;
#pragma unroll
  for (int n = 0; n < 4; n++) {
    int c = wn * 64 + n * 16 + (l & 15);
    float gbv = gb[c], gav = ga[c];
#pragma unroll
    for (int m = 0; m < 4; m++) {
      int rloc = wm * 64 + m * 16 + ((l >> 4) << 2);
#pragma unroll
      for (int q = 0; q < 4; q++) {
        float gv = gacc[m][n][q] + gbv;
        g[(size_t)(mBase + rloc + q) * DGAT + c] = gv;
        ep[m][q] += gv * gav;
      }
    }
  }
#pragma unroll
  for (int m = 0; m < 4; m++)
#pragma unroll
    for (int q = 0; q < 4; q++) {
      float v = ep[m][q];
      v += __shfl_xor(v, 8, 16);
      v += __shfl_xor(v, 4, 16);
      v += __shfl_xor(v, 2, 16);
      v += __shfl_xor(v, 1, 16);
      if ((l & 15) == 0) {
        int rloc = wm * 64 + m * 16 + ((l >> 4) << 2) + q;
        eP[rloc * 2 + wn] = v;
      }
    }
  __syncthreads();
  if (t < 128) e[mBase + t] = eP[t * 2] + eP[t * 2 + 1];
}

// ---------------- segment softmax-pool + residual + segment max ----------------
// one wave per segment
__global__ __launch_bounds__(256) void k_seg(
    const float* __restrict__ e, const float* __restrict__ g, const float* __restrict__ h2,
    const int* __restrict__ rs, float* __restrict__ obj) {
  const int w = threadIdx.x >> 6, l = threadIdx.x & 63;
  const int s = blockIdx.x * 4 + w;
  const int r0 = rs[s], r1 = rs[s + 1];
  float m = -3.4e38f;
  for (int r = r0; r < r1; ++r) m = fmaxf(m, e[r]);
  float den = 0.f;
  f32x2 p = {0.f, 0.f};
  for (int r = r0; r < r1; ++r) {
    float wr = __expf(e[r] - m);
    den += wr;
    f32x2 gv = *(const f32x2*)(g + (size_t)r * DGAT + l * 2);
    p[0] += wr * gv[0];
    p[1] += wr * gv[1];
  }
  float inv = 1.f / den;
  p[0] *= inv; p[1] *= inv;
  f32x2 om = {0.f, 0.f};  // relu output >= 0, at least one row
  for (int r = r0; r < r1; ++r) {
    f32x2 hv = *(const f32x2*)(h2 + (size_t)r * DGAT + l * 2);
    float a0 = fmaxf(hv[0] + p[0], 0.f);
    float a1 = fmaxf(hv[1] + p[1], 0.f);
    om[0] = fmaxf(om[0], a0);
    om[1] = fmaxf(om[1], a1);
  }
  *(f32x2*)(obj + (size_t)s * DGAT + l * 2) = om;
}

// ---------------- projection + L2 norm: out = normalize(obj @ pw + pb) ----------------
// 16 obj rows per block, 256 threads (one output column each)
__global__ __launch_bounds__(256) void k_proj(
    const float* __restrict__ obj, const float* __restrict__ pw, const float* __restrict__ pb,
    float* __restrict__ out) {
  __shared__ float objs[16 * 128];
  __shared__ float red[16 * 4];
  const int t = threadIdx.x;
  const int gBase = blockIdx.x * 16;
#pragma unroll
  for (int i = 0; i < 8; i++) {
    int idx = i * 256 + t;
    objs[idx] = obj[(size_t)gBase * 128 + idx];
  }
  __syncthreads();
  float acc[16];
#pragma unroll
  for (int r = 0; r < 16; r++) acc[r] = 0.f;
  for (int k = 0; k < 128; k++) {
    float pwv = pw[k * 256 + t];
#pragma unroll
    for (int r = 0; r < 16; r++) acc[r] += objs[r * 128 + k] * pwv;
  }
  const float pbv = pb[t];
  const int w = t >> 6, l = t & 63;
#pragma unroll
  for (int r = 0; r < 16; r++) {
    acc[r] += pbv;
    float s2 = acc[r] * acc[r];
#pragma unroll
    for (int off = 32; off >= 1; off >>= 1) s2 += __shfl_xor(s2, off, 64);
    if (l == 0) red[r * 4 + w] = s2;
  }
  __syncthreads();
#pragma unroll
  for (int r = 0; r < 16; r++) {
    float tot = red[r * 4] + red[r * 4 + 1] + red[r * 4 + 2] + red[r * 4 + 3];
    float rinv = 1.f / (sqrtf(tot) + 1e-9f);
    out[(size_t)(gBase + r) * 256 + t] = acc[r] * rinv;
  }
}

extern "C" void kernel_launch(void* const* d_in, const int* in_sizes, int n_in,
                              void* d_out, int out_size, void* d_ws, size_t ws_size,
                              hipStream_t stream) {
  const float* x    = (const float*)d_in[0];
  const int*   seg  = (const int*)d_in[1];
  const float* w2   = (const float*)d_in[2];
  const float* b2   = (const float*)d_in[3];
  const float* bn_g = (const float*)d_in[4];
  const float* bn_b = (const float*)d_in[5];
  const float* bn_m = (const float*)d_in[6];
  const float* bn_v = (const float*)d_in[7];
  const float* w3   = (const float*)d_in[8];
  const float* b3   = (const float*)d_in[9];
  const float* gw   = (const float*)d_in[10];
  const float* gb   = (const float*)d_in[11];
  const float* ga   = (const float*)d_in[12];
  const float* pw   = (const float*)d_in[13];
  const float* pb   = (const float*)d_in[14];

  char* ws = (char*)d_ws;
  bf16*  w2t = (bf16*)(ws + OFF_W2T);
  bf16*  w3t = (bf16*)(ws + OFF_W3T);
  bf16*  gwt = (bf16*)(ws + OFF_GWT);
  float* bnS = (float*)(ws + OFF_BNS);
  float* bnB = (float*)(ws + OFF_BNB);
  int*   rs  = (int*)(ws + OFF_RS);
  bf16*  h1  = (bf16*)(ws + OFF_H1);
  float* h2  = (float*)(ws + OFF_H2);
  float* g   = (float*)(ws + OFF_G);
  float* e   = (float*)(ws + OFF_E);
  float* obj = (float*)(ws + OFF_OBJ);
  float* out = (float*)d_out;

  k_prep<<<512, 256, 0, stream>>>(w2, w3, gw, b2, bn_g, bn_b, bn_m, bn_v, w2t, w3t, gwt, bnS, bnB);
  k_rowstart<<<NROWS / 256, 256, 0, stream>>>(seg, rs);
  k_gemm1<<<NROWS / 128, 256, 0, stream>>>(x, w2t, bnS, bnB, h1);
  k_gemm23<<<NROWS / 128, 256, 0, stream>>>(h1, w3t, gwt, b3, gb, ga, h2, g, e);
  k_seg<<<GSEG / 4, 256, 0, stream>>>(e, g, h2, rs, obj);
  k_proj<<<GSEG / 16, 256, 0, stream>>>(obj, pw, pb, out);
}